// Round 7
// baseline (513.002 us; speedup 1.0000x reference)
//
#include <hip/hip_runtime.h>
#include <cstdint>
#include <cstddef>

// Problem constants (reference: M=8192, IN=4096, OUT=4096)
#define M_DIM 8192
#define K_DIM 4096
#define N_DIM 4096

// GEMM tile geometry
#define BM 256
#define BN 256
#define BK 64
#define NT (K_DIM / BK)  // 64 K-tiles

typedef unsigned short u16;
typedef __bf16 bf16x8 __attribute__((ext_vector_type(8)));
typedef u16 u16x8 __attribute__((ext_vector_type(8)));
typedef float f32x4 __attribute__((ext_vector_type(4)));

// small int -> bf16 (exact for |i| <= 8)
__device__ __forceinline__ u16 i2bf(int i) {
  return (u16)(__builtin_bit_cast(uint32_t, (float)i) >> 16);
}
// packed f32x2 -> bf16x2 (RNE), single instruction
__device__ __forceinline__ uint32_t cvt2(float a, float b) {
  uint32_t r;
  asm("v_cvt_pk_bf16_f32 %0, %1, %2" : "=v"(r) : "v"(a), "v"(b));
  return r;
}

#define WBLKS 8192  // N*(K/2)/4/256 blocks for the weight-dequant prep

// ---- Weight prep only: packed-int4 -> bf16 integer weights (40 MB total) --
// (x fp32->bf16 conversion is fused into the GEMM's A-staging path now.)
__global__ __launch_bounds__(256) void prep(const int* __restrict__ wp,
                                            u16* __restrict__ wb) {
  size_t t = (size_t)blockIdx.x * 256 + threadIdx.x;
  int4 p = ((const int4*)wp)[t];
  u16x8 r;
  int v;
  v = p.x ^ 0x88; r[0] = i2bf((v << 28) >> 28); r[1] = i2bf((v << 24) >> 28);
  v = p.y ^ 0x88; r[2] = i2bf((v << 28) >> 28); r[3] = i2bf((v << 24) >> 28);
  v = p.z ^ 0x88; r[4] = i2bf((v << 28) >> 28); r[5] = i2bf((v << 24) >> 28);
  v = p.w ^ 0x88; r[6] = i2bf((v << 28) >> 28); r[7] = i2bf((v << 24) >> 28);
  ((u16x8*)wb)[t] = r;
}

// ---- Fused bf16 gemm: A = f32 x, converted in-kernel during staging --------
// C[m][n] = (sum_k x[m][k]*B[n][k]) * scale[n] + bias[n]
//
// Structure: 256x256 tile, BK=64, 8 waves (2M x 4N), wave tile 128x64,
// mfma_f32_16x16x32_bf16, round-6's rotated-fragment schedule.
//
// Staging:
//  * B: global_load_lds (bf16 weights from prep), 2 halves x 2 loads = 4/tile,
//    counted-vmcnt (never drains in main loop).
//  * A: REGISTER-staged f32 (8x global_load_dwordx4 -> 16 VGPR), converted
//    with v_cvt_pk_bf16_f32 and ds_write_b128'd into swizzled LDS. The
//    compiler inserts the exact vmcnt for the A-reg consumers, which keeps
//    the younger B loads in flight (FIFO).
//
// Per-iter ledger (audited):
//  top: outstanding = B(T)4 (oldest) + A(T+1)8. s_waitcnt vmcnt(8)+lgkmcnt(0)
//       -> B(T) landed; own ds_writes of A(T) drained. Raw s_barrier publishes
//       tile T (A via ds_writes everywhere + each wave's lgkm0; B via each
//       wave's vmcnt) AND certifies tile T-1 reads retired -> the (T+1)-parity
//       A/B buffers are free for writing below.
//  body: issue B(T+1) gload_lds (post-barrier, into free slot); clusters 1-2;
//       cvt+ds_write A(T+1) (compiler vmcnt(4)-ish keeps B(T+1) in flight);
//       clusters 3-4; sched_barrier; issue A(T+2) f32 loads (fence preserves
//       FIFO: all B(T+1) precede all A(T+2)); sched_barrier.
//  tail: last iter peeled to vmcnt(0) (only B(NT-1) outstanding).
//
// Swizzle (verified SQ_LDS_BANK_CONFLICT==0): LDS row = 64 u16 = 128 B = 32
// banks; staging covers row srow, chunk slot tid&7 with globally pre-swizzled
// source chunk ((tid&7)^(srow&7)); readers address slot chunk^(lrow&7).
__global__ __launch_bounds__(512, 2) void gemm_w4a16_fused(
    const float* __restrict__ X,    // [M_DIM, K_DIM] f32 activations
    const u16* __restrict__ B,      // [N_DIM, K_DIM] bf16 bits (integer weights)
    const float* __restrict__ scales,
    const float* __restrict__ bias,
    float* __restrict__ C) {
  __shared__ u16 sA[2][2 * 8192];  // [dbuf][half*8192 + row*64 + slot*8], 64 KiB
  __shared__ u16 sB[2][2 * 8192];  // 64 KiB                      total 128 KiB

  const int tid = threadIdx.x;
  const int lane = tid & 63;
  const int wave = tid >> 6;          // 0..7
  const int m0 = blockIdx.y * BM;
  const int n0 = blockIdx.x * BN;

  const int wm = (wave >> 2) * 128;   // 0 or 128   (2 M-waves)
  const int wn = (wave & 3) * 64;     // 0,64,128,192 (4 N-waves)
  const int lrow = lane & 15;         // row within a 16x16 frag
  const int quad = lane >> 4;         // k-chunk selector; m-subrow for C/D
  const int brw0 = wn & 64;           // B row base within its half

  f32x4 acc[8][4] = {};

  // Staging map: thread tid covers rows srow (+64,+128,+192), chunk slot
  // tid&7; global source chunk XOR-swizzled by srow&7 (rows step by 64 ==
  // 0 mod 8 -> key invariant).
  const int srow = tid >> 3;                    // 0..63
  const int schunk = ((tid & 7) ^ (srow & 7)) * 8;   // element offset
  const float* gx = X + (size_t)(m0 + srow) * K_DIM + schunk;
  const u16* gb = B + (size_t)(n0 + srow) * K_DIM + schunk;
  const int dst0 = tid * 16;                    // LDS byte offset (linear slots)

#define GLDS(gp, lp)                                                      \
  __builtin_amdgcn_global_load_lds(                                       \
      (const __attribute__((address_space(1))) void*)(gp),                \
      (__attribute__((address_space(3))) void*)(lp), 16, 0, 0)

  // B half-tile stages (gload_lds direct, 2 loads each).
  auto stB0 = [&](int nb, int T) {
    const u16* g = gb + (size_t)T * BK;
    char* d = (char*)sB[nb] + dst0;
    GLDS(g, d);
    GLDS(g + (size_t)64 * K_DIM, d + 8192);
  };
  auto stB1 = [&](int nb, int T) {
    const u16* g = gb + (size_t)128 * K_DIM + (size_t)T * BK;
    char* d = (char*)sB[nb] + 16384 + dst0;
    GLDS(g, d);
    GLDS(g + (size_t)64 * K_DIM, d + 8192);
  };

  // A f32 chunks in registers: 4 chunks (half h, row-pair r) x 8 floats.
  struct C8 { float4 lo, hi; };
  C8 c00, c01, c10, c11;
  auto ldA = [&](int T) {  // 8 global_load_dwordx4 -> named regs
    const float* p = gx + (size_t)T * BK;
    c00.lo = *(const float4*)(p);
    c00.hi = *(const float4*)(p + 4);
    const float* p1 = p + (size_t)64 * K_DIM;
    c01.lo = *(const float4*)(p1);
    c01.hi = *(const float4*)(p1 + 4);
    const float* p2 = p + (size_t)128 * K_DIM;
    c10.lo = *(const float4*)(p2);
    c10.hi = *(const float4*)(p2 + 4);
    const float* p3 = p + (size_t)192 * K_DIM;
    c11.lo = *(const float4*)(p3);
    c11.hi = *(const float4*)(p3 + 4);
  };
  auto wrA = [&](int nb) {  // cvt_pk + 4x ds_write_b128 into swizzled slots
    uint4 q;
    char* d = (char*)sA[nb] + dst0;
    q.x = cvt2(c00.lo.x, c00.lo.y); q.y = cvt2(c00.lo.z, c00.lo.w);
    q.z = cvt2(c00.hi.x, c00.hi.y); q.w = cvt2(c00.hi.z, c00.hi.w);
    *(uint4*)(d) = q;
    q.x = cvt2(c01.lo.x, c01.lo.y); q.y = cvt2(c01.lo.z, c01.lo.w);
    q.z = cvt2(c01.hi.x, c01.hi.y); q.w = cvt2(c01.hi.z, c01.hi.w);
    *(uint4*)(d + 8192) = q;
    q.x = cvt2(c10.lo.x, c10.lo.y); q.y = cvt2(c10.lo.z, c10.lo.w);
    q.z = cvt2(c10.hi.x, c10.hi.y); q.w = cvt2(c10.hi.z, c10.hi.w);
    *(uint4*)(d + 16384) = q;
    q.x = cvt2(c11.lo.x, c11.lo.y); q.y = cvt2(c11.lo.z, c11.lo.w);
    q.z = cvt2(c11.hi.x, c11.hi.y); q.w = cvt2(c11.hi.z, c11.hi.w);
    *(uint4*)(d + 24576) = q;
  };

  struct frag4 { u16x8 v[4]; };

  // ---- Prologue: A(0)->regs, B(0) staged, A(0) written, A(1)->regs --------
  ldA(0);
  stB0(0, 0); stB1(0, 0);
  wrA(0);                              // compiler vmcnt waits A(0) only
  __builtin_amdgcn_sched_barrier(0);   // FIFO: B(0) issued before A(1)
  ldA(1);

#pragma unroll 1
  for (int T = 0; T < NT; ++T) {
    const int cb = T & 1;
    const int nb = cb ^ 1;
    const bool more = (T + 1 < NT);

    if (more)
      asm volatile("s_waitcnt vmcnt(8) lgkmcnt(0)" ::: "memory");  // B(T) landed
    else
      asm volatile("s_waitcnt vmcnt(0) lgkmcnt(0)" ::: "memory");  // peeled tail
    __builtin_amdgcn_s_barrier();       // raw: A(T+1) f32 loads stay in flight
    __builtin_amdgcn_sched_barrier(0);  // anti-hoist fence

    if (more) stB0(nb, T + 1);          // into slot certified free by barrier

    const u16* aH = sA[cb] + ((wave >> 2) ? 8192 : 0);
    const u16* bH = sB[cb] + ((wn & 128) ? 8192 : 0);

    const int kc0 = ((0 * 4 + quad) ^ (lrow & 7)) * 8;
    const int kc1 = ((1 * 4 + quad) ^ (lrow & 7)) * 8;

    auto ldAf = [&](int ih, int kc) {
      frag4 f;
#pragma unroll
      for (int i = 0; i < 4; ++i)
        f.v[i] = *(const u16x8*)(aH + (ih * 64 + i * 16 + lrow) * BK + kc);
      return f;
    };
    auto ldBf = [&](int kc) {
      frag4 f;
#pragma unroll
      for (int j = 0; j < 4; ++j)
        f.v[j] = *(const u16x8*)(bH + (brw0 + j * 16 + lrow) * BK + kc);
      return f;
    };

    // Rotated-fragment schedule (round-6, proven): reads for sub-phase p+1
    // issue before MFMA of p; cvt+write A(T+1) placed to hide under clusters.
    frag4 bfr0 = ldBf(kc0);
    frag4 afA = ldAf(0, kc0);

    frag4 afB = ldAf(1, kc0);
    __builtin_amdgcn_s_setprio(1);
#pragma unroll
    for (int i = 0; i < 4; ++i)
#pragma unroll
      for (int j = 0; j < 4; ++j)
        acc[i][j] = __builtin_amdgcn_mfma_f32_16x16x32_bf16(
            __builtin_bit_cast(bf16x8, afA.v[i]),
            __builtin_bit_cast(bf16x8, bfr0.v[j]), acc[i][j], 0, 0, 0);
    __builtin_amdgcn_s_setprio(0);

    frag4 afA2 = ldAf(0, kc1);
    frag4 bfr1 = ldBf(kc1);
    if (more) stB1(nb, T + 1);
    __builtin_amdgcn_s_setprio(1);
#pragma unroll
    for (int i = 0; i < 4; ++i)
#pragma unroll
      for (int j = 0; j < 4; ++j)
        acc[4 + i][j] = __builtin_amdgcn_mfma_f32_16x16x32_bf16(
            __builtin_bit_cast(bf16x8, afB.v[i]),
            __builtin_bit_cast(bf16x8, bfr0.v[j]), acc[4 + i][j], 0, 0, 0);
    __builtin_amdgcn_s_setprio(0);

    frag4 afB2 = ldAf(1, kc1);
    if (more) wrA(nb);                  // A(T+1): cvt hides under cluster 3
    __builtin_amdgcn_s_setprio(1);
#pragma unroll
    for (int i = 0; i < 4; ++i)
#pragma unroll
      for (int j = 0; j < 4; ++j)
        acc[i][j] = __builtin_amdgcn_mfma_f32_16x16x32_bf16(
            __builtin_bit_cast(bf16x8, afA2.v[i]),
            __builtin_bit_cast(bf16x8, bfr1.v[j]), acc[i][j], 0, 0, 0);
    __builtin_amdgcn_s_setprio(0);

    __builtin_amdgcn_s_setprio(1);
#pragma unroll
    for (int i = 0; i < 4; ++i)
#pragma unroll
      for (int j = 0; j < 4; ++j)
        acc[4 + i][j] = __builtin_amdgcn_mfma_f32_16x16x32_bf16(
            __builtin_bit_cast(bf16x8, afB2.v[i]),
            __builtin_bit_cast(bf16x8, bfr1.v[j]), acc[4 + i][j], 0, 0, 0);
    __builtin_amdgcn_s_setprio(0);

    __builtin_amdgcn_sched_barrier(0);  // FIFO fence: all B(T+1) before A(T+2)
    if (T + 2 < NT) ldA(T + 2);
    __builtin_amdgcn_sched_barrier(0);  // anti-sink fence (iter ends)
  }

  // Epilogue: C/D layout col = lane&15 (n), row = quad*4 + reg (m). Apply
  // per-output-row scale + bias here (keeps MFMA inputs exact integers).
#pragma unroll
  for (int j = 0; j < 4; ++j) {
    const int n = n0 + wn + j * 16 + lrow;
    const float sc = scales[n];
    const float bi = bias[n];
#pragma unroll
    for (int i = 0; i < 8; ++i) {
      const int m = m0 + wm + i * 16 + quad * 4;
      float* cp = &C[(size_t)m * N_DIM + n];
#pragma unroll
      for (int r = 0; r < 4; ++r)
        cp[(size_t)r * N_DIM] = acc[i][j][r] * sc + bi;
    }
  }
#undef GLDS
}

// ---------------- Fallback (ws too small): fp32 direct, correct but slow ----
__global__ __launch_bounds__(256) void fallback_w4a16(
    const float* __restrict__ x, const int* __restrict__ wp,
    const float* __restrict__ scales, const float* __restrict__ bias,
    float* __restrict__ out) {
  const int n = blockIdx.x * 256 + threadIdx.x;
  const int m = blockIdx.y;
  const float* xr = x + (size_t)m * K_DIM;
  const int* wr = wp + (size_t)n * (K_DIM / 2);
  float acc = 0.f;
  for (int j = 0; j < K_DIM / 2; ++j) {
    int w = wr[j] ^ 0x88;
    float lo = (float)((w << 28) >> 28);
    float hi = (float)((w << 24) >> 28);
    acc += xr[2 * j] * lo + xr[2 * j + 1] * hi;
  }
  out[(size_t)m * N_DIM + n] = acc * scales[n] + bias[n];
}

extern "C" void kernel_launch(void* const* d_in, const int* in_sizes, int n_in,
                              void* d_out, int out_size, void* d_ws, size_t ws_size,
                              hipStream_t stream) {
  const float* x = (const float*)d_in[0];
  const int* wp = (const int*)d_in[1];
  const float* sc = (const float*)d_in[2];
  const float* bi = (const float*)d_in[3];
  float* out = (float*)d_out;

  const size_t wb_elems = (size_t)N_DIM * K_DIM;           // 32 MiB as u16
  const size_t need = wb_elems * sizeof(u16);

  if (ws_size >= need) {
    u16* wb = (u16*)d_ws;
    prep<<<WBLKS, 256, 0, stream>>>(wp, wb);
    gemm_w4a16_fused<<<dim3(N_DIM / BN, M_DIM / BM), 512, 0, stream>>>(x, wb, sc, bi, out);
  } else {
    fallback_w4a16<<<dim3(N_DIM / 256, M_DIM), 256, 0, stream>>>(x, wp, sc, bi, out);
  }
}